// Round 5
// baseline (418.077 us; speedup 1.0000x reference)
//
#include <hip/hip_runtime.h>
#include <hip/hip_bf16.h>
#include <math.h>

// Problem constants
#define N_ 256
#define C_ 256
#define V_ 25
#define T_ 20
#define C4_ 64
#define O_ 256
#define VT_ 500
#define EPS_ 1e-5f

typedef unsigned short ushort_t;
typedef unsigned short us4 __attribute__((ext_vector_type(4)));
typedef short short8 __attribute__((ext_vector_type(8)));
typedef float f32x4 __attribute__((ext_vector_type(4)));

__device__ __forceinline__ float bf2f(ushort_t u) {
    unsigned int v = ((unsigned int)u) << 16;
    return __builtin_bit_cast(float, v);
}
__device__ __forceinline__ ushort_t f2bf(float f) {
    unsigned int u = __builtin_bit_cast(unsigned int, f);
    unsigned int r = u + 0x7fffu + ((u >> 16) & 1u);
    return (ushort_t)(r >> 16);
}

// LDS-only barrier: drain lgkmcnt but leave vmcnt (private-register global
// loads) in flight across the barrier.
__device__ __forceinline__ void bar_lds() {
    __builtin_amdgcn_sched_barrier(0);
    asm volatile("s_waitcnt lgkmcnt(0)" ::: "memory");
    __builtin_amdgcn_s_barrier();
    __builtin_amdgcn_sched_barrier(0);
}

// ---------------- Kernel 1: pool (coalesced) + weight prep ----------------
// Blocks 0..8191: pooling (8 nc-rows each).
// 8192..8255: Wc2 -> bf16.  8256..8271: Wl2 -> bf16.  8272..8463: Wl1 -> awl bf16 (permuted).
__global__ __launch_bounds__(256) void k_pool(const float* __restrict__ x,
                                              float* __restrict__ pooled,
                                              const float* __restrict__ Wc2,
                                              ushort_t* __restrict__ wbf,
                                              const float* __restrict__ Wl1,
                                              ushort_t* __restrict__ awl,
                                              const float* __restrict__ Wl2,
                                              ushort_t* __restrict__ wl2bf) {
    int tid = threadIdx.x;
    if (blockIdx.x >= 8272) {
        // awl[c4*768 + k*256 + c] = bf16(Wl1[(c4*256+c)*3 + k]); 49152 elems
        int o = (blockIdx.x - 8272) * 256 + tid;
        int c4 = o / 768;
        int rem = o - c4 * 768;
        int k = rem >> 8, c = rem & 255;
        awl[o] = f2bf(Wl1[(c4 * 256 + c) * 3 + k]);
        return;
    }
    if (blockIdx.x >= 8256) {
        int i = (blockIdx.x - 8256) * 256 + tid;     // us4 index, 4096 total
        f32x4 v = ((const f32x4*)Wl2)[i];
        us4 o; o.x = f2bf(v.x); o.y = f2bf(v.y); o.z = f2bf(v.z); o.w = f2bf(v.w);
        ((us4*)wl2bf)[i] = o;
        return;
    }
    if (blockIdx.x >= 8192) {
        int i = (blockIdx.x - 8192) * 256 + tid;     // us4 index, 16384 total
        f32x4 v = ((const f32x4*)Wc2)[i];
        us4 o; o.x = f2bf(v.x); o.y = f2bf(v.y); o.z = f2bf(v.z); o.w = f2bf(v.w);
        ((us4*)wbf)[i] = o;
        return;
    }
    __shared__ float xs[8][504];
    const f32x4* src = (const f32x4*)(x + (size_t)blockIdx.x * 8 * VT_);
    for (int i = tid; i < 1000; i += 256) {
        int r = i / 125, cidx = (i % 125) * 4;
        *(f32x4*)&xs[r][cidx] = src[i];
    }
    __syncthreads();
    if (tid < 160) {
        int r = tid / 20, t = tid % 20;
        float s = 0.f;
#pragma unroll
        for (int v = 0; v < V_; ++v) s += xs[r][v * T_ + t];
        pooled[blockIdx.x * 160 + tid] = s * 0.04f;   // pooled[nc][t]
    }
}

// ---------------- Kernel 2: G (VALU, uniform weights) + L (MFMA) per n ----------------
__global__ __launch_bounds__(256) void k_gl(const float* __restrict__ pooled,
                                            const float* __restrict__ Wg1,
                                            const float* __restrict__ Wg2,
                                            const float* __restrict__ bng,
                                            const float* __restrict__ bnl,
                                            const ushort_t* __restrict__ awl,
                                            const ushort_t* __restrict__ wl2bf,
                                            float* __restrict__ kern,
                                            float* __restrict__ l2out) {
    __shared__ __align__(16) char smem[76288];
    float (*pp)[22] = (float (*)[22])smem;
    float* sl = (float*)(smem + 22528);
    float* bl = (float*)(smem + 22528 + 256);
    char* lsT = smem + 23040;    // 32 rows x 128 B, bf16 [t][c4], XOR-swizzled
    char* bpt = smem + 27136;    // 32 rows x 1536 B, bf16 [t][k*256+c], XOR-swizzled

    int tid = threadIdx.x;
    int n = blockIdx.x;

    {
        const f32x4* pn = (const f32x4*)(pooled + n * (C_ * T_));
#pragma unroll
        for (int q = 0; q < 5; ++q) {
            int id = q * 256 + tid;
            int c = id / 5, qq = id % 5;
            f32x4 v = pn[id];
            pp[c][qq * 4 + 0] = v.x; pp[c][qq * 4 + 1] = v.y;
            pp[c][qq * 4 + 2] = v.z; pp[c][qq * 4 + 3] = v.w;
        }
    }
    if (tid < C4_) {
        float g = bnl[tid], b = bnl[64 + tid];
        float m = bnl[128 + tid], v = bnl[192 + tid];
        float s = g * rsqrtf(v + EPS_);
        sl[tid] = s; bl[tid] = b - m * s;
    }
    {
        unsigned int* z = (unsigned int*)lsT;
        for (int i = tid; i < 384; i += 256) z[640 + i] = 0u;
    }
    __syncthreads();

    float p[20];
#pragma unroll
    for (int t = 0; t < 20; ++t) p[t] = pp[tid][t];

    // G branch (thread = c); weights read with wave-uniform addresses -> s_load
    {
        float l0 = 0.f, l1 = 0.f, l2 = 0.f;
#pragma unroll 4
        for (int j = 0; j < 40; ++j) {
            float h = 0.f;
#pragma unroll
            for (int t = 0; t < 20; ++t) h = fmaf(Wg1[j * 20 + t], p[t], h);
            float g = bng[j], b = bng[40 + j];
            float m = bng[80 + j], v = bng[120 + j];
            float s = g * rsqrtf(v + EPS_);
            h = fmaxf(fmaf(h, s, b - m * s), 0.f);
            l0 = fmaf(Wg2[j], h, l0);
            l1 = fmaf(Wg2[40 + j], h, l1);
            l2 = fmaf(Wg2[80 + j], h, l2);
        }
        float mx = fmaxf(l0, fmaxf(l1, l2));
        float e0 = __expf(l0 - mx), e1 = __expf(l1 - mx), e2 = __expf(l2 - mx);
        float inv = 1.f / (e0 + e1 + e2);
        float* kp = kern + (n * C_ + tid) * 3;
        kp[0] = e0 * inv; kp[1] = e1 * inv; kp[2] = e2 * inv;
    }

    // build bpadT[t][k*256+c] = pooled[c][t+k-1] (0 outside), swizzled b16 writes
    {
        int c = tid;
#pragma unroll
        for (int k = 0; k < 3; ++k) {
            int col2base = (k * 256 + c) * 2;
#pragma unroll
            for (int t = 0; t < 20; ++t) {
                int i = t + k - 1;
                float v = (i >= 0 && i < 20) ? p[i] : 0.f;
                int byte = t * 1536 + (col2base ^ ((t & 7) << 4));
                *(ushort_t*)(bpt + byte) = f2bf(v);
            }
        }
    }
    __syncthreads();

    int lane = tid & 63, wave = tid >> 6;
    int mrow = lane & 15, kof = (lane >> 4) * 8, prow = (lane >> 4) * 4;

    // conv1 MFMA: L[c4][t] = sum_K awl[c4][K] * bpadT[t][K], K = 768
    {
        f32x4 acc0 = (f32x4){0.f, 0.f, 0.f, 0.f};
        f32x4 acc1 = (f32x4){0.f, 0.f, 0.f, 0.f};
        int swz = ((mrow & 7) << 4);
#pragma unroll 4
        for (int kk = 0; kk < 768; kk += 32) {
            short8 af = *(const short8*)(awl + (wave * 16 + mrow) * 768 + kk + kof);
            short8 b0 = *(const short8*)(bpt + mrow * 1536 + (((kk + kof) * 2) ^ swz));
            short8 b1 = *(const short8*)(bpt + (16 + mrow) * 1536 + (((kk + kof) * 2) ^ swz));
            acc0 = __builtin_amdgcn_mfma_f32_16x16x32_bf16(af, b0, acc0, 0, 0, 0);
            acc1 = __builtin_amdgcn_mfma_f32_16x16x32_bf16(af, b1, acc1, 0, 0, 0);
        }
        f32x4 sv = *(const f32x4*)(sl + wave * 16 + prow);
        f32x4 bv = *(const f32x4*)(bl + wave * 16 + prow);
#pragma unroll
        for (int nt = 0; nt < 2; ++nt) {
            int t = nt * 16 + (lane & 15);
            if (t < 20) {
                f32x4 a = nt ? acc1 : acc0;
#pragma unroll
                for (int r = 0; r < 4; ++r) {
                    int c4 = wave * 16 + prow + r;
                    float v = fmaxf(fmaf(a[r], sv[r], bv[r]), 0.f);
                    int byte = t * 128 + ((c4 * 2) ^ ((t & 7) << 4));
                    *(ushort_t*)(lsT + byte) = f2bf(v);
                }
            }
        }
    }
    __syncthreads();

    // conv2 MFMA: l2[c][t] = sigmoid( sum_{c4} wl2bf[c][c4] * lsT[t][c4] ), K = 64
    {
        f32x4 acc[4][2];
#pragma unroll
        for (int mtl = 0; mtl < 4; ++mtl)
#pragma unroll
            for (int nt = 0; nt < 2; ++nt) acc[mtl][nt] = (f32x4){0.f, 0.f, 0.f, 0.f};
        int swz = ((mrow & 7) << 4);
#pragma unroll
        for (int kk = 0; kk < 64; kk += 32) {
            short8 af[4], bfr[2];
#pragma unroll
            for (int mtl = 0; mtl < 4; ++mtl)
                af[mtl] = *(const short8*)(wl2bf + (wave * 64 + mtl * 16 + mrow) * 64 + kk + kof);
#pragma unroll
            for (int nt = 0; nt < 2; ++nt)
                bfr[nt] = *(const short8*)(lsT + (nt * 16 + mrow) * 128 + (((kk + kof) * 2) ^ swz));
#pragma unroll
            for (int mtl = 0; mtl < 4; ++mtl)
#pragma unroll
                for (int nt = 0; nt < 2; ++nt)
                    acc[mtl][nt] = __builtin_amdgcn_mfma_f32_16x16x32_bf16(af[mtl], bfr[nt], acc[mtl][nt], 0, 0, 0);
        }
#pragma unroll
        for (int nt = 0; nt < 2; ++nt) {
            int t = nt * 16 + (lane & 15);
            if (t < 20) {
#pragma unroll
                for (int mtl = 0; mtl < 4; ++mtl) {
#pragma unroll
                    for (int r = 0; r < 4; ++r) {
                        int c = wave * 64 + mtl * 16 + prow + r;
                        float v = acc[mtl][nt][r];
                        l2out[(n * C_ + c) * T_ + t] = 1.f / (1.f + __expf(-v));
                    }
                }
            }
        }
    }
}

// ---------------- Kernel 3: persistent per-n, grid(256) x 512 threads ----------------
// Double-buffered yT[2][100][YSTRIDE] bf16 in STATIC LDS (105,600 B -> 1 block/CU,
// 8 waves). Static (not dynamic) shared: dynamic allocations >64 KiB can fail the
// launch without hipFuncSetAttribute (not callable under graph capture); static is
// checked against the 160 KiB group segment at compile time (m194 precedent).
// Per 100-col tile: issue next tile's global loads -> GEMM current tile (pure
// LDS+reg: af fragments persist in VGPRs for the whole kernel) -> convert/conv
// into the other buffer. vmcnt stays nonzero across all barriers (lgkm-only).
#define YSTRIDE 264
#define YBUF 26400   // ushorts per buffer (100*264)

__global__ __launch_bounds__(512, 2) void k_main(const float* __restrict__ x,
                                                 const ushort_t* __restrict__ wbf,
                                                 const float* __restrict__ bn1p,
                                                 const float* __restrict__ bn2p,
                                                 const float* __restrict__ kern,
                                                 const float* __restrict__ l2g,
                                                 float* __restrict__ out) {
    __shared__ __align__(16) ushort_t yTs[2 * YBUF];   // 105,600 B static

    int tid = threadIdx.x;
    int n = blockIdx.x;
    const float* xn = x + (size_t)n * (C_ * V_ * T_);
    int lane = tid & 63;
    int wave = tid >> 6;
    int mrow = lane & 15;
    int kof = (lane >> 4) * 8;
    int prow = (lane >> 4) * 4;
    int obase = wave * 32;

    // per-c staging params (c = tid&255; upper half duplicates)
    float s1, b1, k0, k1, k2, l2r[20];
    {
        int c = tid & 255;
        float g1 = bn1p[c], be1 = bn1p[256 + c];
        float m1 = bn1p[512 + c], v1 = bn1p[768 + c];
        s1 = g1 * rsqrtf(v1 + EPS_);
        b1 = be1 - m1 * s1;
        const float* kp = kern + (n * C_ + c) * 3;
        k0 = kp[0]; k1 = kp[1]; k2 = kp[2];
        const f32x4* lp = (const f32x4*)(l2g + (n * C_ + c) * T_);
#pragma unroll
        for (int q = 0; q < 5; ++q) {
            f32x4 v = lp[q];
            l2r[q*4+0] = v.x; l2r[q*4+1] = v.y; l2r[q*4+2] = v.z; l2r[q*4+3] = v.w;
        }
    }
    // per-lane bn2 params for GEMM epilogue: lane L holds channel obase + (L&31)
    float s2, b2;
    {
        int c2 = obase + (lane & 31);
        float g2 = bn2p[c2], be2 = bn2p[256 + c2];
        float m2 = bn2p[512 + c2], v2 = bn2p[768 + c2];
        s2 = g2 * rsqrtf(v2 + EPS_);
        b2 = be2 - m2 * s2;
    }

    // af fragments (Wc2) are tile-invariant: load ONCE, keep in 64 VGPRs.
    short8 afr[2][8];
#pragma unroll
    for (int mt = 0; mt < 2; ++mt)
#pragma unroll
        for (int k8 = 0; k8 < 8; ++k8)
            afr[mt][k8] = *(const short8*)(wbf + (obase + mt * 16 + mrow) * C_ + k8 * 32 + kof);

    // global-load offsets for staging: 6400 f32x4 per tile; thread q<12: id=q*512+tid,
    // q=12 only tid<256: id=6144+tid.  id -> c=id/25, qq=id%25.
    int off[13];
#pragma unroll
    for (int q = 0; q < 12; ++q) {
        int id = q * 512 + tid;
        off[q] = (id / 25) * VT_ + (id % 25) * 4;
    }
    off[12] = ((6144 + tid) / 25) * VT_ + ((6144 + tid) % 25) * 4;   // tid<256 only

    const int ctb[7] = {0, 16, 32, 48, 64, 80, 84};

    // ---- prologue: stage tile 0 into buffer 0 ----
    f32x4 ld[13];
#pragma unroll
    for (int q = 0; q < 12; ++q) ld[q] = *(const f32x4*)(xn + off[q]);
    if (tid < 256) ld[12] = *(const f32x4*)(xn + off[12]);

    // convert -> xs layout [c][100] bf16 overlaid on buffer 0
    {
        ushort_t* xs = yTs;
#pragma unroll
        for (int q = 0; q < 12; ++q) {
            int id = q * 512 + tid;
            us4 o; o.x = f2bf(ld[q].x); o.y = f2bf(ld[q].y);
            o.z = f2bf(ld[q].z); o.w = f2bf(ld[q].w);
            *(us4*)(xs + (id / 25) * 100 + (id % 25) * 4) = o;
        }
        if (tid < 256) {
            int id = 6144 + tid;
            us4 o; o.x = f2bf(ld[12].x); o.y = f2bf(ld[12].y);
            o.z = f2bf(ld[12].z); o.w = f2bf(ld[12].w);
            *(us4*)(xs + (id / 25) * 100 + (id % 25) * 4) = o;
        }
    }
    bar_lds();
    // conv rows {v=0/1, v=2/3, v=4(tid<256)} -> yv regs, then rewrite region as yT[0]
    float yv[3][20];
    {
        const ushort_t* xs = yTs;
        int c = tid & 255;
#pragma unroll
        for (int r3 = 0; r3 < 3; ++r3) {
            int v = (r3 < 2) ? (r3 * 2 + (tid >> 8)) : 4;
            if (r3 < 2 || tid < 256) {
                float a[22];
                a[0] = 0.f; a[21] = 0.f;
#pragma unroll
                for (int qq = 0; qq < 5; ++qq) {
                    us4 u = *(const us4*)(xs + c * 100 + v * 20 + qq * 4);
                    a[qq*4 + 1] = bf2f(u.x) + l2r[qq*4 + 0];
                    a[qq*4 + 2] = bf2f(u.y) + l2r[qq*4 + 1];
                    a[qq*4 + 3] = bf2f(u.z) + l2r[qq*4 + 2];
                    a[qq*4 + 4] = bf2f(u.w) + l2r[qq*4 + 3];
                }
#pragma unroll
                for (int t = 0; t < 20; ++t) {
                    float z = fmaf(k0, a[t], fmaf(k1, a[t + 1], k2 * a[t + 2]));
                    yv[r3][t] = fmaxf(fmaf(z, s1, b1), 0.f);
                }
            }
        }
    }
    bar_lds();
    {
        ushort_t* yb = yTs;
        int c = tid & 255;
#pragma unroll
        for (int r3 = 0; r3 < 3; ++r3) {
            int v = (r3 < 2) ? (r3 * 2 + (tid >> 8)) : 4;
            if (r3 < 2 || tid < 256) {
#pragma unroll
                for (int t = 0; t < 20; ++t)
                    yb[(v * 20 + t) * YSTRIDE + c] = f2bf(yv[r3][t]);
            }
        }
    }
    bar_lds();

    int buf = 0;
    float* outn0 = out + (size_t)n * (O_ * VT_);

#pragma unroll 1
    for (int tile = 0; tile < 5; ++tile) {
        // (1) issue next tile's loads (land during GEMM; lgkm-only barriers keep them in flight)
        if (tile < 4) {
#pragma unroll
            for (int q = 0; q < 12; ++q)
                ld[q] = *(const f32x4*)(xn + off[q] + (tile + 1) * 100);
            if (tid < 256) ld[12] = *(const f32x4*)(xn + off[12] + (tile + 1) * 100);
        }
        __builtin_amdgcn_sched_barrier(0);

        // (2) GEMM on yT[buf]: pure LDS + reg (af in VGPRs) -> no VMEM waits
        {
            const ushort_t* yb = yTs + buf * YBUF;
            f32x4 acc[2][7];
#pragma unroll
            for (int mt = 0; mt < 2; ++mt)
#pragma unroll
                for (int j = 0; j < 7; ++j) acc[mt][j] = (f32x4){0.f, 0.f, 0.f, 0.f};
#pragma unroll
            for (int k8 = 0; k8 < 8; ++k8) {
#pragma unroll
                for (int ct = 0; ct < 7; ++ct) {
                    short8 b = *(const short8*)(yb + (ctb[ct] + mrow) * YSTRIDE + k8 * 32 + kof);
                    acc[0][ct] = __builtin_amdgcn_mfma_f32_16x16x32_bf16(afr[0][k8], b, acc[0][ct], 0, 0, 0);
                    acc[1][ct] = __builtin_amdgcn_mfma_f32_16x16x32_bf16(afr[1][k8], b, acc[1][ct], 0, 0, 0);
                }
            }
            // epilogue: bn2+relu, direct stores (params via shfl)
#pragma unroll
            for (int mt = 0; mt < 2; ++mt) {
#pragma unroll
                for (int r = 0; r < 4; ++r) {
                    int lsrc = mt * 16 + prow + r;
                    float s2w = __shfl(s2, lsrc);
                    float b2w = __shfl(b2, lsrc);
                    float* orow = outn0 + (size_t)(obase + lsrc) * VT_ + tile * 100;
#pragma unroll
                    for (int j = 0; j < 7; ++j) {
                        if (!(j == 6 && mrow < 12)) {
                            orow[ctb[j] + mrow] =
                                fmaxf(fmaf(acc[mt][j][r], s2w, b2w), 0.f);
                        }
                    }
                }
            }
        }

        // (3) convert staged regs -> xs overlay on yT[buf^1]
        if (tile < 4) {
            ushort_t* xs = yTs + (buf ^ 1) * YBUF;
#pragma unroll
            for (int q = 0; q < 12; ++q) {
                int id = q * 512 + tid;
                us4 o; o.x = f2bf(ld[q].x); o.y = f2bf(ld[q].y);
                o.z = f2bf(ld[q].z); o.w = f2bf(ld[q].w);
                *(us4*)(xs + (id / 25) * 100 + (id % 25) * 4) = o;
            }
            if (tid < 256) {
                int id = 6144 + tid;
                us4 o; o.x = f2bf(ld[12].x); o.y = f2bf(ld[12].y);
                o.z = f2bf(ld[12].z); o.w = f2bf(ld[12].w);
                *(us4*)(xs + (id / 25) * 100 + (id % 25) * 4) = o;
            }
        }
        bar_lds();   // A: xs complete; also all GEMM ds_reads of yT[buf] drained

        // (4a) conv xs -> yv regs
        if (tile < 4) {
            const ushort_t* xs = yTs + (buf ^ 1) * YBUF;
            int c = tid & 255;
#pragma unroll
            for (int r3 = 0; r3 < 3; ++r3) {
                int v = (r3 < 2) ? (r3 * 2 + (tid >> 8)) : 4;
                if (r3 < 2 || tid < 256) {
                    float a[22];
                    a[0] = 0.f; a[21] = 0.f;
#pragma unroll
                    for (int qq = 0; qq < 5; ++qq) {
                        us4 u = *(const us4*)(xs + c * 100 + v * 20 + qq * 4);
                        a[qq*4 + 1] = bf2f(u.x) + l2r[qq*4 + 0];
                        a[qq*4 + 2] = bf2f(u.y) + l2r[qq*4 + 1];
                        a[qq*4 + 3] = bf2f(u.z) + l2r[qq*4 + 2];
                        a[qq*4 + 4] = bf2f(u.w) + l2r[qq*4 + 3];
                    }
#pragma unroll
                    for (int t = 0; t < 20; ++t) {
                        float z = fmaf(k0, a[t], fmaf(k1, a[t + 1], k2 * a[t + 2]));
                        yv[r3][t] = fmaxf(fmaf(z, s1, b1), 0.f);
                    }
                }
            }
        }
        bar_lds();   // B: all xs reads done

        // (4b) write conv output as yT[buf^1][p][c]
        if (tile < 4) {
            ushort_t* yb = yTs + (buf ^ 1) * YBUF;
            int c = tid & 255;
#pragma unroll
            for (int r3 = 0; r3 < 3; ++r3) {
                int v = (r3 < 2) ? (r3 * 2 + (tid >> 8)) : 4;
                if (r3 < 2 || tid < 256) {
#pragma unroll
                    for (int t = 0; t < 20; ++t)
                        yb[(v * 20 + t) * YSTRIDE + c] = f2bf(yv[r3][t]);
                }
            }
        }
        bar_lds();   // C: yT[buf^1] ready for next GEMM
        buf ^= 1;
    }
}

extern "C" void kernel_launch(void* const* d_in, const int* in_sizes, int n_in,
                              void* d_out, int out_size, void* d_ws, size_t ws_size,
                              hipStream_t stream) {
    const float* x   = (const float*)d_in[0];
    const float* Wg1 = (const float*)d_in[1];
    const float* Wg2 = (const float*)d_in[2];
    const float* Wl1 = (const float*)d_in[3];
    const float* Wl2 = (const float*)d_in[4];
    const float* Wc2 = (const float*)d_in[5];
    const float* bng = (const float*)d_in[6];
    const float* bnl = (const float*)d_in[7];
    const float* bn1p = (const float*)d_in[8];
    const float* bn2p = (const float*)d_in[9];
    float* out = (float*)d_out;

    float* ws = (float*)d_ws;
    float* pooled = ws;                                   // N*C*T = 1310720 f
    float* kern   = ws + 1310720;                         // N*C*3 = 196608 f
    float* l2g    = ws + 1310720 + 196608;                // N*C*T = 1310720 f
    ushort_t* wbf   = (ushort_t*)(ws + 2818048);          // 65536 bf16 (32768 f)
    ushort_t* wl2bf = (ushort_t*)(ws + 2818048 + 32768);  // 16384 bf16 (8192 f)
    ushort_t* awl   = (ushort_t*)(ws + 2818048 + 40960);  // 49152 bf16 (24576 f)

    k_pool<<<dim3(8464), dim3(256), 0, stream>>>(x, pooled, Wc2, wbf, Wl1, awl, Wl2, wl2bf);
    k_gl<<<dim3(N_), dim3(256), 0, stream>>>(pooled, Wg1, Wg2, bng, bnl, awl, wl2bf, kern, l2g);
    k_main<<<dim3(N_), dim3(512), 0, stream>>>(x, wbf, bn1p, bn2p, kern, l2g, out);
}

// Round 6
// 377.975 us; speedup vs baseline: 1.1061x; 1.1061x over previous
//
#include <hip/hip_runtime.h>
#include <hip/hip_bf16.h>
#include <math.h>

// Problem constants
#define N_ 256
#define C_ 256
#define V_ 25
#define T_ 20
#define C4_ 64
#define O_ 256
#define VT_ 500
#define EPS_ 1e-5f

typedef unsigned short ushort_t;
typedef unsigned short us4 __attribute__((ext_vector_type(4)));
typedef short short8 __attribute__((ext_vector_type(8)));
typedef float f32x4 __attribute__((ext_vector_type(4)));

__device__ __forceinline__ float bf2f(ushort_t u) {
    unsigned int v = ((unsigned int)u) << 16;
    return __builtin_bit_cast(float, v);
}
__device__ __forceinline__ ushort_t f2bf(float f) {
    unsigned int u = __builtin_bit_cast(unsigned int, f);
    unsigned int r = u + 0x7fffu + ((u >> 16) & 1u);
    return (ushort_t)(r >> 16);
}

// LDS-only barrier: drain lgkmcnt but leave vmcnt (private-register global
// loads) in flight across the barrier.
__device__ __forceinline__ void bar_lds() {
    __builtin_amdgcn_sched_barrier(0);
    asm volatile("s_waitcnt lgkmcnt(0)" ::: "memory");
    __builtin_amdgcn_s_barrier();
    __builtin_amdgcn_sched_barrier(0);
}

// ---------------- Kernel 1: pool (coalesced) + weight prep ----------------
// Blocks 0..8191: pooling (8 nc-rows each).
// 8192..8255: Wc2 -> bf16.  8256..8271: Wl2 -> bf16.  8272..8463: Wl1 -> awl bf16 (permuted).
__global__ __launch_bounds__(256) void k_pool(const float* __restrict__ x,
                                              float* __restrict__ pooled,
                                              const float* __restrict__ Wc2,
                                              ushort_t* __restrict__ wbf,
                                              const float* __restrict__ Wl1,
                                              ushort_t* __restrict__ awl,
                                              const float* __restrict__ Wl2,
                                              ushort_t* __restrict__ wl2bf) {
    int tid = threadIdx.x;
    if (blockIdx.x >= 8272) {
        // awl[c4*768 + k*256 + c] = bf16(Wl1[(c4*256+c)*3 + k]); 49152 elems
        int o = (blockIdx.x - 8272) * 256 + tid;
        int c4 = o / 768;
        int rem = o - c4 * 768;
        int k = rem >> 8, c = rem & 255;
        awl[o] = f2bf(Wl1[(c4 * 256 + c) * 3 + k]);
        return;
    }
    if (blockIdx.x >= 8256) {
        int i = (blockIdx.x - 8256) * 256 + tid;     // us4 index, 4096 total
        f32x4 v = ((const f32x4*)Wl2)[i];
        us4 o; o.x = f2bf(v.x); o.y = f2bf(v.y); o.z = f2bf(v.z); o.w = f2bf(v.w);
        ((us4*)wl2bf)[i] = o;
        return;
    }
    if (blockIdx.x >= 8192) {
        int i = (blockIdx.x - 8192) * 256 + tid;     // us4 index, 16384 total
        f32x4 v = ((const f32x4*)Wc2)[i];
        us4 o; o.x = f2bf(v.x); o.y = f2bf(v.y); o.z = f2bf(v.z); o.w = f2bf(v.w);
        ((us4*)wbf)[i] = o;
        return;
    }
    __shared__ float xs[8][504];
    const f32x4* src = (const f32x4*)(x + (size_t)blockIdx.x * 8 * VT_);
    for (int i = tid; i < 1000; i += 256) {
        int r = i / 125, cidx = (i % 125) * 4;
        *(f32x4*)&xs[r][cidx] = src[i];
    }
    __syncthreads();
    if (tid < 160) {
        int r = tid / 20, t = tid % 20;
        float s = 0.f;
#pragma unroll
        for (int v = 0; v < V_; ++v) s += xs[r][v * T_ + t];
        pooled[blockIdx.x * 160 + tid] = s * 0.04f;   // pooled[nc][t]
    }
}

// ---------------- Kernel 2: G (VALU, uniform weights) + L (MFMA) per n ----------------
__global__ __launch_bounds__(256) void k_gl(const float* __restrict__ pooled,
                                            const float* __restrict__ Wg1,
                                            const float* __restrict__ Wg2,
                                            const float* __restrict__ bng,
                                            const float* __restrict__ bnl,
                                            const ushort_t* __restrict__ awl,
                                            const ushort_t* __restrict__ wl2bf,
                                            float* __restrict__ kern,
                                            float* __restrict__ l2out) {
    __shared__ __align__(16) char smem[76288];
    float (*pp)[22] = (float (*)[22])smem;
    float* sl = (float*)(smem + 22528);
    float* bl = (float*)(smem + 22528 + 256);
    char* lsT = smem + 23040;    // 32 rows x 128 B, bf16 [t][c4], XOR-swizzled
    char* bpt = smem + 27136;    // 32 rows x 1536 B, bf16 [t][k*256+c], XOR-swizzled

    int tid = threadIdx.x;
    int n = blockIdx.x;

    {
        const f32x4* pn = (const f32x4*)(pooled + n * (C_ * T_));
#pragma unroll
        for (int q = 0; q < 5; ++q) {
            int id = q * 256 + tid;
            int c = id / 5, qq = id % 5;
            f32x4 v = pn[id];
            pp[c][qq * 4 + 0] = v.x; pp[c][qq * 4 + 1] = v.y;
            pp[c][qq * 4 + 2] = v.z; pp[c][qq * 4 + 3] = v.w;
        }
    }
    if (tid < C4_) {
        float g = bnl[tid], b = bnl[64 + tid];
        float m = bnl[128 + tid], v = bnl[192 + tid];
        float s = g * rsqrtf(v + EPS_);
        sl[tid] = s; bl[tid] = b - m * s;
    }
    {
        unsigned int* z = (unsigned int*)lsT;
        for (int i = tid; i < 384; i += 256) z[640 + i] = 0u;
    }
    __syncthreads();

    float p[20];
#pragma unroll
    for (int t = 0; t < 20; ++t) p[t] = pp[tid][t];

    // G branch (thread = c); weights read with wave-uniform addresses -> s_load
    {
        float l0 = 0.f, l1 = 0.f, l2 = 0.f;
#pragma unroll 4
        for (int j = 0; j < 40; ++j) {
            float h = 0.f;
#pragma unroll
            for (int t = 0; t < 20; ++t) h = fmaf(Wg1[j * 20 + t], p[t], h);
            float g = bng[j], b = bng[40 + j];
            float m = bng[80 + j], v = bng[120 + j];
            float s = g * rsqrtf(v + EPS_);
            h = fmaxf(fmaf(h, s, b - m * s), 0.f);
            l0 = fmaf(Wg2[j], h, l0);
            l1 = fmaf(Wg2[40 + j], h, l1);
            l2 = fmaf(Wg2[80 + j], h, l2);
        }
        float mx = fmaxf(l0, fmaxf(l1, l2));
        float e0 = __expf(l0 - mx), e1 = __expf(l1 - mx), e2 = __expf(l2 - mx);
        float inv = 1.f / (e0 + e1 + e2);
        float* kp = kern + (n * C_ + tid) * 3;
        kp[0] = e0 * inv; kp[1] = e1 * inv; kp[2] = e2 * inv;
    }

    // build bpadT[t][k*256+c] = pooled[c][t+k-1] (0 outside), swizzled b16 writes
    {
        int c = tid;
#pragma unroll
        for (int k = 0; k < 3; ++k) {
            int col2base = (k * 256 + c) * 2;
#pragma unroll
            for (int t = 0; t < 20; ++t) {
                int i = t + k - 1;
                float v = (i >= 0 && i < 20) ? p[i] : 0.f;
                int byte = t * 1536 + (col2base ^ ((t & 7) << 4));
                *(ushort_t*)(bpt + byte) = f2bf(v);
            }
        }
    }
    __syncthreads();

    int lane = tid & 63, wave = tid >> 6;
    int mrow = lane & 15, kof = (lane >> 4) * 8, prow = (lane >> 4) * 4;

    // conv1 MFMA: L[c4][t] = sum_K awl[c4][K] * bpadT[t][K], K = 768
    {
        f32x4 acc0 = (f32x4){0.f, 0.f, 0.f, 0.f};
        f32x4 acc1 = (f32x4){0.f, 0.f, 0.f, 0.f};
        int swz = ((mrow & 7) << 4);
#pragma unroll 4
        for (int kk = 0; kk < 768; kk += 32) {
            short8 af = *(const short8*)(awl + (wave * 16 + mrow) * 768 + kk + kof);
            short8 b0 = *(const short8*)(bpt + mrow * 1536 + (((kk + kof) * 2) ^ swz));
            short8 b1 = *(const short8*)(bpt + (16 + mrow) * 1536 + (((kk + kof) * 2) ^ swz));
            acc0 = __builtin_amdgcn_mfma_f32_16x16x32_bf16(af, b0, acc0, 0, 0, 0);
            acc1 = __builtin_amdgcn_mfma_f32_16x16x32_bf16(af, b1, acc1, 0, 0, 0);
        }
        f32x4 sv = *(const f32x4*)(sl + wave * 16 + prow);
        f32x4 bv = *(const f32x4*)(bl + wave * 16 + prow);
#pragma unroll
        for (int nt = 0; nt < 2; ++nt) {
            int t = nt * 16 + (lane & 15);
            if (t < 20) {
                f32x4 a = nt ? acc1 : acc0;
#pragma unroll
                for (int r = 0; r < 4; ++r) {
                    int c4 = wave * 16 + prow + r;
                    float v = fmaxf(fmaf(a[r], sv[r], bv[r]), 0.f);
                    int byte = t * 128 + ((c4 * 2) ^ ((t & 7) << 4));
                    *(ushort_t*)(lsT + byte) = f2bf(v);
                }
            }
        }
    }
    __syncthreads();

    // conv2 MFMA: l2[c][t] = sigmoid( sum_{c4} wl2bf[c][c4] * lsT[t][c4] ), K = 64
    {
        f32x4 acc[4][2];
#pragma unroll
        for (int mtl = 0; mtl < 4; ++mtl)
#pragma unroll
            for (int nt = 0; nt < 2; ++nt) acc[mtl][nt] = (f32x4){0.f, 0.f, 0.f, 0.f};
        int swz = ((mrow & 7) << 4);
#pragma unroll
        for (int kk = 0; kk < 64; kk += 32) {
            short8 af[4], bfr[2];
#pragma unroll
            for (int mtl = 0; mtl < 4; ++mtl)
                af[mtl] = *(const short8*)(wl2bf + (wave * 64 + mtl * 16 + mrow) * 64 + kk + kof);
#pragma unroll
            for (int nt = 0; nt < 2; ++nt)
                bfr[nt] = *(const short8*)(lsT + (nt * 16 + mrow) * 128 + (((kk + kof) * 2) ^ swz));
#pragma unroll
            for (int mtl = 0; mtl < 4; ++mtl)
#pragma unroll
                for (int nt = 0; nt < 2; ++nt)
                    acc[mtl][nt] = __builtin_amdgcn_mfma_f32_16x16x32_bf16(af[mtl], bfr[nt], acc[mtl][nt], 0, 0, 0);
        }
#pragma unroll
        for (int nt = 0; nt < 2; ++nt) {
            int t = nt * 16 + (lane & 15);
            if (t < 20) {
#pragma unroll
                for (int mtl = 0; mtl < 4; ++mtl) {
#pragma unroll
                    for (int r = 0; r < 4; ++r) {
                        int c = wave * 64 + mtl * 16 + prow + r;
                        float v = acc[mtl][nt][r];
                        l2out[(n * C_ + c) * T_ + t] = 1.f / (1.f + __expf(-v));
                    }
                }
            }
        }
    }
}

// ---------------- Kernel 3: persistent per-n, grid(256) x 512 threads ----------------
// Three LDS regions (static, 156,800 B total < 160 KiB):
//   xs  [256][100] bf16 (51,200 B)  - raw tile staging
//   yT0/yT1 [100][YSTRIDE] bf16 (2 x 52,800 B) - conv output double buffer
// Pipeline per tile t: issue loads(t+2) -> GEMM(yT[buf], tile t) + stores ->
// conv xs(t+1) -> yT[buf^1] -> bar -> xs <- ld(t+2) -> bar.  Loads stream in
// flight under GEMM+conv (lgkm-only barriers); stores drain under conv.
// __launch_bounds__(512, 1): round-5 evidence shows (512,2) capped VGPR at 128
// and the ~250-reg state spilled (+260 MB scratch traffic). (512,1) allows 256.
#define YSTRIDE 264
#define YBUF 26400   // ushorts per yT buffer (100*264)

__global__ __launch_bounds__(512, 1) void k_main(const float* __restrict__ x,
                                                 const ushort_t* __restrict__ wbf,
                                                 const float* __restrict__ bn1p,
                                                 const float* __restrict__ bn2p,
                                                 const float* __restrict__ kern,
                                                 const float* __restrict__ l2g,
                                                 float* __restrict__ out) {
    __shared__ __align__(16) char smem[156800];
    ushort_t* xs = (ushort_t*)smem;                       // [c][100]
    // yT[buf] base: smem + 51200 + buf*52800

    int tid = threadIdx.x;
    int n = blockIdx.x;
    const float* xn = x + (size_t)n * (C_ * V_ * T_);
    int lane = tid & 63;
    int wave = tid >> 6;
    int half = tid >> 8;        // 0/1
    int cc = tid & 255;         // conv channel
    int mrow = lane & 15;
    int kof = (lane >> 4) * 8;
    int prow = (lane >> 4) * 4;
    int obase = wave * 32;

    // per-c staging params (upper half duplicates)
    float s1, b1, k0, k1, k2, l2r[20];
    {
        float g1 = bn1p[cc], be1 = bn1p[256 + cc];
        float m1 = bn1p[512 + cc], v1 = bn1p[768 + cc];
        s1 = g1 * rsqrtf(v1 + EPS_);
        b1 = be1 - m1 * s1;
        const float* kp = kern + (n * C_ + cc) * 3;
        k0 = kp[0]; k1 = kp[1]; k2 = kp[2];
        const f32x4* lp = (const f32x4*)(l2g + (n * C_ + cc) * T_);
#pragma unroll
        for (int q = 0; q < 5; ++q) {
            f32x4 v = lp[q];
            l2r[q*4+0] = v.x; l2r[q*4+1] = v.y; l2r[q*4+2] = v.z; l2r[q*4+3] = v.w;
        }
    }
    // per-lane bn2 params for GEMM epilogue: lane L holds channel obase + (L&31)
    float s2, b2;
    {
        int c2 = obase + (lane & 31);
        float g2 = bn2p[c2], be2 = bn2p[256 + c2];
        float m2 = bn2p[512 + c2], v2 = bn2p[768 + c2];
        s2 = g2 * rsqrtf(v2 + EPS_);
        b2 = be2 - m2 * s2;
    }

    // af fragments (Wc2) are tile-invariant: load ONCE, keep in 32 VGPRs.
    short8 afr[2][8];
#pragma unroll
    for (int mt = 0; mt < 2; ++mt)
#pragma unroll
        for (int k8 = 0; k8 < 8; ++k8)
            afr[mt][k8] = *(const short8*)(wbf + (obase + mt * 16 + mrow) * C_ + k8 * 32 + kof);

    // staging offsets: 6400 f32x4/tile; q<12: id=q*512+tid; q=12 only tid<256.
    int off[13];
#pragma unroll
    for (int q = 0; q < 12; ++q) {
        int id = q * 512 + tid;
        off[q] = (id / 25) * VT_ + (id % 25) * 4;
    }
    off[12] = ((6144 + tid) / 25) * VT_ + ((6144 + tid) % 25) * 4;

    const int ctb[7] = {0, 16, 32, 48, 64, 80, 84};

#define ISSUE_LD(TILE)                                                        \
    {                                                                         \
        _Pragma("unroll")                                                     \
        for (int q = 0; q < 12; ++q)                                          \
            ld[q] = *(const f32x4*)(xn + off[q] + (TILE) * 100);              \
        if (half == 0) ld[12] = *(const f32x4*)(xn + off[12] + (TILE) * 100); \
    }

#define WRITE_XS()                                                            \
    {                                                                         \
        _Pragma("unroll")                                                     \
        for (int q = 0; q < 12; ++q) {                                        \
            int id = q * 512 + tid;                                           \
            us4 o; o.x = f2bf(ld[q].x); o.y = f2bf(ld[q].y);                  \
            o.z = f2bf(ld[q].z); o.w = f2bf(ld[q].w);                         \
            *(us4*)(xs + (id / 25) * 100 + (id % 25) * 4) = o;                \
        }                                                                     \
        if (half == 0) {                                                      \
            int id = 6144 + tid;                                              \
            us4 o; o.x = f2bf(ld[12].x); o.y = f2bf(ld[12].y);                \
            o.z = f2bf(ld[12].z); o.w = f2bf(ld[12].w);                       \
            *(us4*)(xs + (id / 25) * 100 + (id % 25) * 4) = o;                \
        }                                                                     \
    }

#define CONV_TO(YB)                                                           \
    {                                                                         \
        ushort_t* yb_ = (YB);                                                 \
        _Pragma("unroll")                                                     \
        for (int r3 = 0; r3 < 3; ++r3) {                                      \
            int v = (r3 < 2) ? (r3 * 2 + half) : 4;                           \
            if (r3 < 2 || half == 0) {                                        \
                float a[22];                                                  \
                a[0] = 0.f; a[21] = 0.f;                                      \
                _Pragma("unroll")                                             \
                for (int qq = 0; qq < 5; ++qq) {                              \
                    us4 u = *(const us4*)(xs + cc * 100 + v * 20 + qq * 4);   \
                    a[qq*4 + 1] = bf2f(u.x) + l2r[qq*4 + 0];                  \
                    a[qq*4 + 2] = bf2f(u.y) + l2r[qq*4 + 1];                  \
                    a[qq*4 + 3] = bf2f(u.z) + l2r[qq*4 + 2];                  \
                    a[qq*4 + 4] = bf2f(u.w) + l2r[qq*4 + 3];                  \
                }                                                             \
                _Pragma("unroll")                                             \
                for (int t = 0; t < 20; ++t) {                                \
                    float z = fmaf(k0, a[t], fmaf(k1, a[t + 1], k2 * a[t + 2]));\
                    yb_[(v * 20 + t) * YSTRIDE + cc] =                        \
                        f2bf(fmaxf(fmaf(z, s1, b1), 0.f));                    \
                }                                                             \
            }                                                                 \
        }                                                                     \
    }

    // ---- prologue ----
    f32x4 ld[13];
    ISSUE_LD(0);
    WRITE_XS();                       // tile0 -> xs (vmcnt waits auto)
    bar_lds();
    ISSUE_LD(1);                      // tile1 in flight under conv
    CONV_TO((ushort_t*)(smem + 51200));   // tile0 -> yT[0]
    bar_lds();                        // yT[0] ready; xs reads done
    WRITE_XS();                       // tile1 -> xs
    bar_lds();

    int buf = 0;
    float* outn0 = out + (size_t)n * (O_ * VT_);

#pragma unroll 1
    for (int tile = 0; tile < 5; ++tile) {
        if (tile < 3) ISSUE_LD(tile + 2);
        __builtin_amdgcn_sched_barrier(0);

        // GEMM on yT[buf]: pure LDS + reg (af resident) -> no VMEM waits
        {
            const ushort_t* yb = (const ushort_t*)(smem + 51200) + buf * YBUF;
            f32x4 acc[2][7];
#pragma unroll
            for (int mt = 0; mt < 2; ++mt)
#pragma unroll
                for (int j = 0; j < 7; ++j) acc[mt][j] = (f32x4){0.f, 0.f, 0.f, 0.f};
#pragma unroll
            for (int k8 = 0; k8 < 8; ++k8) {
#pragma unroll
                for (int ct = 0; ct < 7; ++ct) {
                    short8 b = *(const short8*)(yb + (ctb[ct] + mrow) * YSTRIDE + k8 * 32 + kof);
                    acc[0][ct] = __builtin_amdgcn_mfma_f32_16x16x32_bf16(afr[0][k8], b, acc[0][ct], 0, 0, 0);
                    acc[1][ct] = __builtin_amdgcn_mfma_f32_16x16x32_bf16(afr[1][k8], b, acc[1][ct], 0, 0, 0);
                }
            }
            // epilogue: bn2+relu, direct stores (params via shfl); stores drain under conv
#pragma unroll
            for (int mt = 0; mt < 2; ++mt) {
#pragma unroll
                for (int r = 0; r < 4; ++r) {
                    int lsrc = mt * 16 + prow + r;
                    float s2w = __shfl(s2, lsrc);
                    float b2w = __shfl(b2, lsrc);
                    float* orow = outn0 + (size_t)(obase + lsrc) * VT_ + tile * 100;
#pragma unroll
                    for (int j = 0; j < 7; ++j) {
                        if (!(j == 6 && mrow < 12)) {
                            orow[ctb[j] + mrow] =
                                fmaxf(fmaf(acc[mt][j][r], s2w, b2w), 0.f);
                        }
                    }
                }
            }
        }

        if (tile < 4) {
            CONV_TO((ushort_t*)(smem + 51200) + (buf ^ 1) * YBUF);   // tile+1
            bar_lds();               // xs consumed; yT[buf^1] complete; GEMM reads drained
            if (tile < 3) WRITE_XS();   // tile+2 -> xs (loads from this iter's ISSUE_LD)
            bar_lds();               // xs visible for next conv
        }
        buf ^= 1;
    }
#undef ISSUE_LD
#undef WRITE_XS
#undef CONV_TO
}

extern "C" void kernel_launch(void* const* d_in, const int* in_sizes, int n_in,
                              void* d_out, int out_size, void* d_ws, size_t ws_size,
                              hipStream_t stream) {
    const float* x   = (const float*)d_in[0];
    const float* Wg1 = (const float*)d_in[1];
    const float* Wg2 = (const float*)d_in[2];
    const float* Wl1 = (const float*)d_in[3];
    const float* Wl2 = (const float*)d_in[4];
    const float* Wc2 = (const float*)d_in[5];
    const float* bng = (const float*)d_in[6];
    const float* bnl = (const float*)d_in[7];
    const float* bn1p = (const float*)d_in[8];
    const float* bn2p = (const float*)d_in[9];
    float* out = (float*)d_out;

    float* ws = (float*)d_ws;
    float* pooled = ws;                                   // N*C*T = 1310720 f
    float* kern   = ws + 1310720;                         // N*C*3 = 196608 f
    float* l2g    = ws + 1310720 + 196608;                // N*C*T = 1310720 f
    ushort_t* wbf   = (ushort_t*)(ws + 2818048);          // 65536 bf16 (32768 f)
    ushort_t* wl2bf = (ushort_t*)(ws + 2818048 + 32768);  // 16384 bf16 (8192 f)
    ushort_t* awl   = (ushort_t*)(ws + 2818048 + 40960);  // 49152 bf16 (24576 f)

    k_pool<<<dim3(8464), dim3(256), 0, stream>>>(x, pooled, Wc2, wbf, Wl1, awl, Wl2, wl2bf);
    k_gl<<<dim3(N_), dim3(256), 0, stream>>>(pooled, Wg1, Wg2, bng, bnl, awl, wl2bf, kern, l2g);
    k_main<<<dim3(N_), dim3(512), 0, stream>>>(x, wbf, bn1p, bn2p, kern, l2g, out);
}

// Round 7
// 350.043 us; speedup vs baseline: 1.1944x; 1.0798x over previous
//
#include <hip/hip_runtime.h>
#include <hip/hip_bf16.h>
#include <math.h>

// Problem constants
#define N_ 256
#define C_ 256
#define V_ 25
#define T_ 20
#define C4_ 64
#define O_ 256
#define VT_ 500
#define EPS_ 1e-5f

typedef unsigned short ushort_t;
typedef unsigned short us4 __attribute__((ext_vector_type(4)));
typedef short short8 __attribute__((ext_vector_type(8)));
typedef float f32x4 __attribute__((ext_vector_type(4)));

__device__ __forceinline__ float bf2f(ushort_t u) {
    unsigned int v = ((unsigned int)u) << 16;
    return __builtin_bit_cast(float, v);
}
__device__ __forceinline__ ushort_t f2bf(float f) {
    unsigned int u = __builtin_bit_cast(unsigned int, f);
    unsigned int r = u + 0x7fffu + ((u >> 16) & 1u);
    return (ushort_t)(r >> 16);
}

// LDS-only barrier: drain lgkmcnt but leave vmcnt (private-register global
// loads) in flight across the barrier.
__device__ __forceinline__ void bar_lds() {
    __builtin_amdgcn_sched_barrier(0);
    asm volatile("s_waitcnt lgkmcnt(0)" ::: "memory");
    __builtin_amdgcn_s_barrier();
    __builtin_amdgcn_sched_barrier(0);
}

// ---------------- Kernel 1: pool (coalesced) + weight prep ----------------
// Blocks 0..8191: pooling (8 nc-rows each).
// 8192..8255: Wc2 -> bf16.  8256..8271: Wl2 -> bf16.  8272..8463: Wl1 -> awl bf16 (permuted).
__global__ __launch_bounds__(256) void k_pool(const float* __restrict__ x,
                                              float* __restrict__ pooled,
                                              const float* __restrict__ Wc2,
                                              ushort_t* __restrict__ wbf,
                                              const float* __restrict__ Wl1,
                                              ushort_t* __restrict__ awl,
                                              const float* __restrict__ Wl2,
                                              ushort_t* __restrict__ wl2bf) {
    int tid = threadIdx.x;
    if (blockIdx.x >= 8272) {
        // awl[c4*768 + k*256 + c] = bf16(Wl1[(c4*256+c)*3 + k]); 49152 elems
        int o = (blockIdx.x - 8272) * 256 + tid;
        int c4 = o / 768;
        int rem = o - c4 * 768;
        int k = rem >> 8, c = rem & 255;
        awl[o] = f2bf(Wl1[(c4 * 256 + c) * 3 + k]);
        return;
    }
    if (blockIdx.x >= 8256) {
        int i = (blockIdx.x - 8256) * 256 + tid;     // us4 index, 4096 total
        f32x4 v = ((const f32x4*)Wl2)[i];
        us4 o; o.x = f2bf(v.x); o.y = f2bf(v.y); o.z = f2bf(v.z); o.w = f2bf(v.w);
        ((us4*)wl2bf)[i] = o;
        return;
    }
    if (blockIdx.x >= 8192) {
        int i = (blockIdx.x - 8192) * 256 + tid;     // us4 index, 16384 total
        f32x4 v = ((const f32x4*)Wc2)[i];
        us4 o; o.x = f2bf(v.x); o.y = f2bf(v.y); o.z = f2bf(v.z); o.w = f2bf(v.w);
        ((us4*)wbf)[i] = o;
        return;
    }
    __shared__ float xs[8][504];
    const f32x4* src = (const f32x4*)(x + (size_t)blockIdx.x * 8 * VT_);
    for (int i = tid; i < 1000; i += 256) {
        int r = i / 125, cidx = (i % 125) * 4;
        *(f32x4*)&xs[r][cidx] = src[i];
    }
    __syncthreads();
    if (tid < 160) {
        int r = tid / 20, t = tid % 20;
        float s = 0.f;
#pragma unroll
        for (int v = 0; v < V_; ++v) s += xs[r][v * T_ + t];
        pooled[blockIdx.x * 160 + tid] = s * 0.04f;   // pooled[nc][t]
    }
}

// ---------------- Kernel 2: G (VALU, uniform weights) + L (MFMA) per n ----------------
__global__ __launch_bounds__(256) void k_gl(const float* __restrict__ pooled,
                                            const float* __restrict__ Wg1,
                                            const float* __restrict__ Wg2,
                                            const float* __restrict__ bng,
                                            const float* __restrict__ bnl,
                                            const ushort_t* __restrict__ awl,
                                            const ushort_t* __restrict__ wl2bf,
                                            float* __restrict__ kern,
                                            float* __restrict__ l2out) {
    __shared__ __align__(16) char smem[76288];
    float (*pp)[22] = (float (*)[22])smem;
    float* sl = (float*)(smem + 22528);
    float* bl = (float*)(smem + 22528 + 256);
    char* lsT = smem + 23040;    // 32 rows x 128 B, bf16 [t][c4], XOR-swizzled
    char* bpt = smem + 27136;    // 32 rows x 1536 B, bf16 [t][k*256+c], XOR-swizzled

    int tid = threadIdx.x;
    int n = blockIdx.x;

    {
        const f32x4* pn = (const f32x4*)(pooled + n * (C_ * T_));
#pragma unroll
        for (int q = 0; q < 5; ++q) {
            int id = q * 256 + tid;
            int c = id / 5, qq = id % 5;
            f32x4 v = pn[id];
            pp[c][qq * 4 + 0] = v.x; pp[c][qq * 4 + 1] = v.y;
            pp[c][qq * 4 + 2] = v.z; pp[c][qq * 4 + 3] = v.w;
        }
    }
    if (tid < C4_) {
        float g = bnl[tid], b = bnl[64 + tid];
        float m = bnl[128 + tid], v = bnl[192 + tid];
        float s = g * rsqrtf(v + EPS_);
        sl[tid] = s; bl[tid] = b - m * s;
    }
    {
        unsigned int* z = (unsigned int*)lsT;
        for (int i = tid; i < 384; i += 256) z[640 + i] = 0u;
    }
    __syncthreads();

    float p[20];
#pragma unroll
    for (int t = 0; t < 20; ++t) p[t] = pp[tid][t];

    // G branch (thread = c); weights read with wave-uniform addresses -> s_load
    {
        float l0 = 0.f, l1 = 0.f, l2 = 0.f;
#pragma unroll 4
        for (int j = 0; j < 40; ++j) {
            float h = 0.f;
#pragma unroll
            for (int t = 0; t < 20; ++t) h = fmaf(Wg1[j * 20 + t], p[t], h);
            float g = bng[j], b = bng[40 + j];
            float m = bng[80 + j], v = bng[120 + j];
            float s = g * rsqrtf(v + EPS_);
            h = fmaxf(fmaf(h, s, b - m * s), 0.f);
            l0 = fmaf(Wg2[j], h, l0);
            l1 = fmaf(Wg2[40 + j], h, l1);
            l2 = fmaf(Wg2[80 + j], h, l2);
        }
        float mx = fmaxf(l0, fmaxf(l1, l2));
        float e0 = __expf(l0 - mx), e1 = __expf(l1 - mx), e2 = __expf(l2 - mx);
        float inv = 1.f / (e0 + e1 + e2);
        float* kp = kern + (n * C_ + tid) * 3;
        kp[0] = e0 * inv; kp[1] = e1 * inv; kp[2] = e2 * inv;
    }

    // build bpadT[t][k*256+c] = pooled[c][t+k-1] (0 outside), swizzled b16 writes
    {
        int c = tid;
#pragma unroll
        for (int k = 0; k < 3; ++k) {
            int col2base = (k * 256 + c) * 2;
#pragma unroll
            for (int t = 0; t < 20; ++t) {
                int i = t + k - 1;
                float v = (i >= 0 && i < 20) ? p[i] : 0.f;
                int byte = t * 1536 + (col2base ^ ((t & 7) << 4));
                *(ushort_t*)(bpt + byte) = f2bf(v);
            }
        }
    }
    __syncthreads();

    int lane = tid & 63, wave = tid >> 6;
    int mrow = lane & 15, kof = (lane >> 4) * 8, prow = (lane >> 4) * 4;

    // conv1 MFMA: L[c4][t] = sum_K awl[c4][K] * bpadT[t][K], K = 768
    {
        f32x4 acc0 = (f32x4){0.f, 0.f, 0.f, 0.f};
        f32x4 acc1 = (f32x4){0.f, 0.f, 0.f, 0.f};
        int swz = ((mrow & 7) << 4);
#pragma unroll 4
        for (int kk = 0; kk < 768; kk += 32) {
            short8 af = *(const short8*)(awl + (wave * 16 + mrow) * 768 + kk + kof);
            short8 b0 = *(const short8*)(bpt + mrow * 1536 + (((kk + kof) * 2) ^ swz));
            short8 b1 = *(const short8*)(bpt + (16 + mrow) * 1536 + (((kk + kof) * 2) ^ swz));
            acc0 = __builtin_amdgcn_mfma_f32_16x16x32_bf16(af, b0, acc0, 0, 0, 0);
            acc1 = __builtin_amdgcn_mfma_f32_16x16x32_bf16(af, b1, acc1, 0, 0, 0);
        }
        f32x4 sv = *(const f32x4*)(sl + wave * 16 + prow);
        f32x4 bv = *(const f32x4*)(bl + wave * 16 + prow);
#pragma unroll
        for (int nt = 0; nt < 2; ++nt) {
            int t = nt * 16 + (lane & 15);
            if (t < 20) {
                f32x4 a = nt ? acc1 : acc0;
#pragma unroll
                for (int r = 0; r < 4; ++r) {
                    int c4 = wave * 16 + prow + r;
                    float v = fmaxf(fmaf(a[r], sv[r], bv[r]), 0.f);
                    int byte = t * 128 + ((c4 * 2) ^ ((t & 7) << 4));
                    *(ushort_t*)(lsT + byte) = f2bf(v);
                }
            }
        }
    }
    __syncthreads();

    // conv2 MFMA: l2[c][t] = sigmoid( sum_{c4} wl2bf[c][c4] * lsT[t][c4] ), K = 64
    {
        f32x4 acc[4][2];
#pragma unroll
        for (int mtl = 0; mtl < 4; ++mtl)
#pragma unroll
            for (int nt = 0; nt < 2; ++nt) acc[mtl][nt] = (f32x4){0.f, 0.f, 0.f, 0.f};
        int swz = ((mrow & 7) << 4);
#pragma unroll
        for (int kk = 0; kk < 64; kk += 32) {
            short8 af[4], bfr[2];
#pragma unroll
            for (int mtl = 0; mtl < 4; ++mtl)
                af[mtl] = *(const short8*)(wl2bf + (wave * 64 + mtl * 16 + mrow) * 64 + kk + kof);
#pragma unroll
            for (int nt = 0; nt < 2; ++nt)
                bfr[nt] = *(const short8*)(lsT + (nt * 16 + mrow) * 128 + (((kk + kof) * 2) ^ swz));
#pragma unroll
            for (int mtl = 0; mtl < 4; ++mtl)
#pragma unroll
                for (int nt = 0; nt < 2; ++nt)
                    acc[mtl][nt] = __builtin_amdgcn_mfma_f32_16x16x32_bf16(af[mtl], bfr[nt], acc[mtl][nt], 0, 0, 0);
        }
#pragma unroll
        for (int nt = 0; nt < 2; ++nt) {
            int t = nt * 16 + (lane & 15);
            if (t < 20) {
#pragma unroll
                for (int mtl = 0; mtl < 4; ++mtl) {
#pragma unroll
                    for (int r = 0; r < 4; ++r) {
                        int c = wave * 64 + mtl * 16 + prow + r;
                        float v = acc[mtl][nt][r];
                        l2out[(n * C_ + c) * T_ + t] = 1.f / (1.f + __expf(-v));
                    }
                }
            }
        }
    }
}

// ---------------- Kernel 3: dyn-conv + bn1 + MFMA 1x1 + bn2, grid (5, N) ----------------
// Barrier-light redesign: thread = c reads its OWN x rows directly from global
// (16B-aligned b128s, stride 2000 B across lanes -> L2-merged; x has no reuse so
// the LDS staging round-trip bought nothing but 10 barriers). Conv in registers
// (f32 inputs now), write yT once, ONE barrier, then the verified GEMM.
#define YSTRIDE 264   // bf16 elems per yT row: 528 B, 16B-aligned, 2-way-bank (free)

template <int NT>
__device__ __forceinline__ void gemm_pass(const ushort_t* __restrict__ yT,
                                          const ushort_t* __restrict__ wbf,
                                          float* __restrict__ outn,
                                          const int (&ctb)[NT], int ov_idx,
                                          int obase, int mrow, int kof, int prow,
                                          float s2, float b2) {
    f32x4 acc[4][NT];
#pragma unroll
    for (int mt = 0; mt < 4; ++mt)
#pragma unroll
        for (int j = 0; j < NT; ++j) acc[mt][j] = (f32x4){0.f, 0.f, 0.f, 0.f};

#pragma unroll 2
    for (int kk = 0; kk < C_; kk += 32) {
        short8 af[4];
        short8 bfr[NT];
#pragma unroll
        for (int mt = 0; mt < 4; ++mt)
            af[mt] = *(const short8*)(wbf + (obase + mt * 16 + mrow) * C_ + kk + kof);
#pragma unroll
        for (int j = 0; j < NT; ++j)
            bfr[j] = *(const short8*)(yT + (ctb[j] + mrow) * YSTRIDE + kk + kof);
#pragma unroll
        for (int mt = 0; mt < 4; ++mt)
#pragma unroll
            for (int j = 0; j < NT; ++j)
                acc[mt][j] = __builtin_amdgcn_mfma_f32_16x16x32_bf16(af[mt], bfr[j], acc[mt][j], 0, 0, 0);
    }

#pragma unroll
    for (int mt = 0; mt < 4; ++mt) {
#pragma unroll
        for (int r = 0; r < 4; ++r) {
            int lsrc = mt * 16 + prow + r;            // lane owning channel obase+lsrc
            float s2w = __shfl(s2, lsrc);
            float b2w = __shfl(b2, lsrc);
            float* orow = outn + (size_t)(obase + lsrc) * VT_;
#pragma unroll
            for (int j = 0; j < NT; ++j) {
                bool skip = (j == ov_idx) && (mrow < 12);   // overlap tile: dup p 84..95
                if (!skip) {
                    float vr = fmaxf(fmaf(acc[mt][j][r], s2w, b2w), 0.f);
                    orow[ctb[j] + mrow] = vr;
                }
            }
        }
    }
}

__global__ __launch_bounds__(256, 3) void k_main(const float* __restrict__ x,
                                                 const ushort_t* __restrict__ wbf,
                                                 const float* __restrict__ bn1p,
                                                 const float* __restrict__ bn2p,
                                                 const float* __restrict__ kern,
                                                 const float* __restrict__ l2g,
                                                 float* __restrict__ out) {
    __shared__ __align__(16) ushort_t yT[100 * YSTRIDE];   // 52,800 B -> 3 blocks/CU

    int tid = threadIdx.x;
    int n = blockIdx.y;
    int vblk = blockIdx.x;
    const float* xn = x + (size_t)n * (C_ * V_ * T_) + vblk * 100;

    // per-c params (thread = c)
    float s1, b1, k0, k1, k2, s2, b2, l2r[20];
    {
        int c = tid;
        float g1 = bn1p[c], be1 = bn1p[256 + c];
        float m1 = bn1p[512 + c], v1 = bn1p[768 + c];
        s1 = g1 * rsqrtf(v1 + EPS_);
        b1 = be1 - m1 * s1;
        float g2 = bn2p[c], be2 = bn2p[256 + c];
        float m2 = bn2p[512 + c], v2 = bn2p[768 + c];
        s2 = g2 * rsqrtf(v2 + EPS_);
        b2 = be2 - m2 * s2;
        const float* kp = kern + (n * C_ + c) * 3;
        k0 = kp[0]; k1 = kp[1]; k2 = kp[2];
        const f32x4* lp = (const f32x4*)(l2g + (n * C_ + c) * T_);
#pragma unroll
        for (int q = 0; q < 5; ++q) {
            f32x4 v = lp[q];
            l2r[q*4+0] = v.x; l2r[q*4+1] = v.y; l2r[q*4+2] = v.z; l2r[q*4+3] = v.w;
        }
    }

    // ---- staging/conv: direct per-thread x reads, conv in regs, write yT ----
#pragma unroll
    for (int vl = 0; vl < 5; ++vl) {
        const float* xrow = xn + tid * VT_ + vl * 20;   // own (c, v) row, 16B-aligned
        f32x4 r[5];
#pragma unroll
        for (int q = 0; q < 5; ++q) r[q] = *(const f32x4*)(xrow + q * 4);
        float a[22];
        a[0] = 0.f; a[21] = 0.f;
#pragma unroll
        for (int q = 0; q < 5; ++q) {
            a[q*4 + 1] = r[q].x + l2r[q*4 + 0];
            a[q*4 + 2] = r[q].y + l2r[q*4 + 1];
            a[q*4 + 3] = r[q].z + l2r[q*4 + 2];
            a[q*4 + 4] = r[q].w + l2r[q*4 + 3];
        }
        ushort_t* ycol = yT + (vl * 20) * YSTRIDE + tid;
#pragma unroll
        for (int t = 0; t < 20; ++t) {
            float z = fmaf(k0, a[t], fmaf(k1, a[t + 1], k2 * a[t + 2]));
            ycol[t * YSTRIDE] = f2bf(fmaxf(fmaf(z, s1, b1), 0.f));
        }
    }
    bar_lds();   // the ONLY barrier: yT complete for all waves

    // ---- MFMA: out[o,p] = sum_c Wc2[o,c] * y[c,p], split into 2 ct-passes ----
    int lane = tid & 63;
    int wave = tid >> 6;
    int mrow = lane & 15;
    int kof = (lane >> 4) * 8;
    int prow = (lane >> 4) * 4;
    int obase = wave * 64;
    float* outn = out + (size_t)n * (O_ * VT_) + vblk * 100;

    {
        const int ctb0[4] = {0, 16, 32, 48};      // p 0..63
        gemm_pass<4>(yT, wbf, outn, ctb0, -1, obase, mrow, kof, prow, s2, b2);
    }
    {
        const int ctb1[3] = {64, 80, 84};         // p 64..95 + overlap tile (96..99)
        gemm_pass<3>(yT, wbf, outn, ctb1, 2, obase, mrow, kof, prow, s2, b2);
    }
}

extern "C" void kernel_launch(void* const* d_in, const int* in_sizes, int n_in,
                              void* d_out, int out_size, void* d_ws, size_t ws_size,
                              hipStream_t stream) {
    const float* x   = (const float*)d_in[0];
    const float* Wg1 = (const float*)d_in[1];
    const float* Wg2 = (const float*)d_in[2];
    const float* Wl1 = (const float*)d_in[3];
    const float* Wl2 = (const float*)d_in[4];
    const float* Wc2 = (const float*)d_in[5];
    const float* bng = (const float*)d_in[6];
    const float* bnl = (const float*)d_in[7];
    const float* bn1p = (const float*)d_in[8];
    const float* bn2p = (const float*)d_in[9];
    float* out = (float*)d_out;

    float* ws = (float*)d_ws;
    float* pooled = ws;                                   // N*C*T = 1310720 f
    float* kern   = ws + 1310720;                         // N*C*3 = 196608 f
    float* l2g    = ws + 1310720 + 196608;                // N*C*T = 1310720 f
    ushort_t* wbf   = (ushort_t*)(ws + 2818048);          // 65536 bf16 (32768 f)
    ushort_t* wl2bf = (ushort_t*)(ws + 2818048 + 32768);  // 16384 bf16 (8192 f)
    ushort_t* awl   = (ushort_t*)(ws + 2818048 + 40960);  // 49152 bf16 (24576 f)

    k_pool<<<dim3(8464), dim3(256), 0, stream>>>(x, pooled, Wc2, wbf, Wl1, awl, Wl2, wl2bf);
    k_gl<<<dim3(N_), dim3(256), 0, stream>>>(pooled, Wg1, Wg2, bng, bnl, awl, wl2bf, kern, l2g);
    k_main<<<dim3(5, N_), dim3(256), 0, stream>>>(x, wbf, bn1p, bn2p, kern, l2g, out);
}